// Round 1
// baseline (216.719 us; speedup 1.0000x reference)
//
#include <hip/hip_runtime.h>
#include <hip/hip_bf16.h>

#define S_LEN 2048
#define E_DIM 1024
#define NH 16
#define HD 64
#define ATTN_SCALE 0.03125f   // 1/sqrt(1024)

typedef __attribute__((ext_vector_type(8))) short short8;
typedef __attribute__((ext_vector_type(8))) unsigned short ushort8;
typedef __attribute__((ext_vector_type(4))) unsigned short ushort4_t;
typedef __attribute__((ext_vector_type(4))) float f32x4;
typedef __attribute__((ext_vector_type(4))) float f4;

__device__ __forceinline__ float bf2f(unsigned short u) {
    unsigned int x = ((unsigned int)u) << 16;
    return __builtin_bit_cast(float, x);
}
__device__ __forceinline__ unsigned short f2bf(float f) {
    unsigned int x = __builtin_bit_cast(unsigned int, f);
    x += 0x7FFFu + ((x >> 16) & 1u);   // RNE
    return (unsigned short)(x >> 16);
}

// ---------------- x f32 -> bf16 ----------------
__global__ __launch_bounds__(256) void k_convert(const float* __restrict__ x,
                                                 unsigned short* __restrict__ xb) {
    size_t i = ((size_t)blockIdx.x * 256 + threadIdx.x) * 8;
    f4 a = *(const f4*)(x + i);
    f4 b = *(const f4*)(x + i + 4);
    ushort8 o;
    o[0] = f2bf(a[0]); o[1] = f2bf(a[1]); o[2] = f2bf(a[2]); o[3] = f2bf(a[3]);
    o[4] = f2bf(b[0]); o[5] = f2bf(b[1]); o[6] = f2bf(b[2]); o[7] = f2bf(b[3]);
    *(ushort8*)(xb + i) = o;
}

// ---------------- W f32 -> bf16 transposed (Wt[n][k] = W[k][n]) ----------------
__global__ __launch_bounds__(256) void k_transw(const float* W0, const float* W1,
                                                const float* W2, const float* W3,
                                                unsigned short* T0, unsigned short* T1,
                                                unsigned short* T2, unsigned short* T3) {
    const float* W; unsigned short* T;
    switch (blockIdx.z) {
        case 0: W = W0; T = T0; break;
        case 1: W = W1; T = T1; break;
        case 2: W = W2; T = T2; break;
        default: W = W3; T = T3; break;
    }
    __shared__ float tile[32][33];
    int tx = threadIdx.x, ty = threadIdx.y;
    int bx = blockIdx.x * 32, by = blockIdx.y * 32;
#pragma unroll
    for (int i = 0; i < 4; i++)
        tile[ty + i * 8][tx] = W[(size_t)(by + ty + i * 8) * E_DIM + bx + tx];
    __syncthreads();
#pragma unroll
    for (int i = 0; i < 4; i++)
        T[(size_t)(bx + ty + i * 8) * E_DIM + by + tx] = f2bf(tile[tx][ty + i * 8]);
}

// ---------------- RoPE cos/sin table: [2048][32] ----------------
__global__ __launch_bounds__(256) void k_rope_table(float* __restrict__ cosT,
                                                    float* __restrict__ sinT) {
    int idx = blockIdx.x * 256 + threadIdx.x;
    int s = idx >> 5, j = idx & 31;
    // inv_freq = 10000^(-j/32)
    float inv = expf(-(float)j * (9.210340371976184f / 32.f));
    float ang = (float)s * inv;
    cosT[idx] = cosf(ang);
    sinT[idx] = sinf(ang);
}

// ---------------- in-place interleaved RoPE on bf16 [4096][1024]; Q also scaled ----------------
__global__ __launch_bounds__(256) void k_rope(unsigned short* Qb, unsigned short* Kb,
                                              const float* __restrict__ cosT,
                                              const float* __restrict__ sinT) {
    unsigned short* T = blockIdx.y ? Kb : Qb;
    float sc = blockIdx.y ? 1.f : ATTN_SCALE;
    size_t chunk = (size_t)blockIdx.x * 256 + threadIdx.x;   // 8 bf16 per chunk
    int row = (int)(chunk >> 7);          // 128 chunks per 1024-wide row
    int colb = (int)(chunk & 127) * 8;
    int s = row & (S_LEN - 1);
    int j0 = (colb & 63) >> 1;            // freq index base within head
    ushort8 u = *(ushort8*)(T + (size_t)row * E_DIM + colb);
#pragma unroll
    for (int i = 0; i < 4; i++) {
        float c = cosT[s * 32 + j0 + i], sn = sinT[s * 32 + j0 + i];
        float e = bf2f(u[2 * i]), o = bf2f(u[2 * i + 1]);
        float oe = (e * c - o * sn) * sc;
        float oo = (e * sn + o * c) * sc;
        u[2 * i] = f2bf(oe);
        u[2 * i + 1] = f2bf(oo);
    }
    *(ushort8*)(T + (size_t)row * E_DIM + colb) = u;
}

// ---------------- bf16 GEMM: C[m][n] = sum_k A[m][k] * Bt[n][k] ----------------
// A: [M][1024] bf16 row-major; Bt: [1024][1024] bf16 (pre-transposed weight)
// 128x128 block tile, 256 threads (4 waves, 2x2), 4x4 16x16x32 frags per wave.
template <bool OUT_F32>
__global__ __launch_bounds__(256) void k_gemm(const unsigned short* __restrict__ A,
                                              const unsigned short* B0,
                                              const unsigned short* B1,
                                              const unsigned short* B2,
                                              void* C0, void* C1, void* C2) {
    const unsigned short* Bp; void* Cp;
    switch (blockIdx.z) {
        case 0: Bp = B0; Cp = C0; break;
        case 1: Bp = B1; Cp = C1; break;
        default: Bp = B2; Cp = C2; break;
    }
    __shared__ unsigned short Alds[128][40];   // +8 pad: 2-way banks on b128 reads
    __shared__ unsigned short Blds[128][40];
    int tid = threadIdx.x;
    int lane = tid & 63, wid = tid >> 6;
    int l15 = lane & 15, lg = lane >> 4;
    int wr = wid >> 1, wc = wid & 1;
    int bm = blockIdx.y, bn = blockIdx.x;
    f32x4 acc[4][4] = {};
    for (int k0 = 0; k0 < E_DIM; k0 += 32) {
#pragma unroll
        for (int i = 0; i < 2; i++) {
            int c = tid + i * 256;        // 512 chunks = 128 rows x 4
            int r = c >> 2, kc = c & 3;
            *(short8*)&Alds[r][kc * 8] =
                *(const short8*)(A + (size_t)(bm * 128 + r) * E_DIM + k0 + kc * 8);
            *(short8*)&Blds[r][kc * 8] =
                *(const short8*)(Bp + (size_t)(bn * 128 + r) * E_DIM + k0 + kc * 8);
        }
        __syncthreads();
        short8 af[4], bfr[4];
#pragma unroll
        for (int mf = 0; mf < 4; mf++)
            af[mf] = *(const short8*)&Alds[wr * 64 + mf * 16 + l15][lg * 8];
#pragma unroll
        for (int nf = 0; nf < 4; nf++)
            bfr[nf] = *(const short8*)&Blds[wc * 64 + nf * 16 + l15][lg * 8];
#pragma unroll
        for (int mf = 0; mf < 4; mf++)
#pragma unroll
            for (int nf = 0; nf < 4; nf++)
                acc[mf][nf] = __builtin_amdgcn_mfma_f32_16x16x32_bf16(
                    af[mf], bfr[nf], acc[mf][nf], 0, 0, 0);
        __syncthreads();
    }
    // epilogue: D row = (lane>>4)*4+reg (A-row), col = lane&15 (B-row)
#pragma unroll
    for (int mf = 0; mf < 4; mf++) {
#pragma unroll
        for (int r = 0; r < 4; r++) {
            size_t row = (size_t)(bm * 128 + wr * 64 + mf * 16 + lg * 4 + r);
#pragma unroll
            for (int nf = 0; nf < 4; nf++) {
                size_t col = (size_t)(bn * 128 + wc * 64 + nf * 16 + l15);
                float v = acc[mf][nf][r];
                if (OUT_F32)
                    ((float*)Cp)[row * E_DIM + col] = v;
                else
                    ((unsigned short*)Cp)[row * E_DIM + col] = f2bf(v);
            }
        }
    }
}

// ---------------- causal flash attention, bf16, per (64 q-rows, head) ----------------
// Swapped QK^T: mfma(K_rows, Q_rows) -> S^T; lane&15 = q, (lane>>4)*4+reg = k.
// Softmax: in-lane over 16 vals + shfl_xor(16,32). P relaid via per-wave padded LDS.
__global__ __launch_bounds__(256) void k_attn(const unsigned short* __restrict__ Q,
                                              const unsigned short* __restrict__ K,
                                              const unsigned short* __restrict__ V,
                                              unsigned short* __restrict__ O) {
    int qt = blockIdx.x;            // 32 q-tiles of 64
    int bh = blockIdx.y;            // 32 (b,h)
    int b = bh >> 4, h = bh & 15;
    __shared__ unsigned short K_lds[64][72];
    __shared__ unsigned short Vt_lds[64][72];    // transposed: [d][k]
    __shared__ unsigned short P_lds[4][16][72];  // per-wave [q][k]
    int tid = threadIdx.x;
    int lane = tid & 63, wid = tid >> 6;
    int l15 = lane & 15, lg = lane >> 4;
    const unsigned short* Qb = Q + (size_t)(b * S_LEN + qt * 64 + wid * 16) * E_DIM + h * 64;
    short8 bq[2];
#pragma unroll
    for (int s2 = 0; s2 < 2; s2++)
        bq[s2] = *(const short8*)(Qb + (size_t)l15 * E_DIM + s2 * 32 + lg * 8);
    f32x4 acc_o[4] = {};
    float m_i = -1e30f, l_i = 0.f;
    int q_glob = qt * 64 + wid * 16 + l15;
    for (int kt = 0; kt <= qt; ++kt) {
        const unsigned short* Kb = K + (size_t)(b * S_LEN + kt * 64) * E_DIM + h * 64;
        const unsigned short* Vb = V + (size_t)(b * S_LEN + kt * 64) * E_DIM + h * 64;
#pragma unroll
        for (int i = 0; i < 2; i++) {
            int c = tid + i * 256;          // 512 chunks = 64 rows x 8
            int r = c >> 3, c8 = c & 7;
            *(short8*)&K_lds[r][c8 * 8] =
                *(const short8*)(Kb + (size_t)r * E_DIM + c8 * 8);
            short8 v = *(const short8*)(Vb + (size_t)r * E_DIM + c8 * 8);
#pragma unroll
            for (int j = 0; j < 8; j++)
                Vt_lds[c8 * 8 + j][r] = (unsigned short)v[j];
        }
        __syncthreads();
        // S^T = K . Q^T  (scale pre-folded into Q)
        f32x4 acc_s[4] = {};
#pragma unroll
        for (int mf = 0; mf < 4; mf++)
#pragma unroll
            for (int s2 = 0; s2 < 2; s2++) {
                short8 a = *(const short8*)&K_lds[mf * 16 + l15][s2 * 32 + lg * 8];
                acc_s[mf] = __builtin_amdgcn_mfma_f32_16x16x32_bf16(
                    a, bq[s2], acc_s[mf], 0, 0, 0);
            }
        // mask + online softmax (lane owns q=l15; its 16 vals cover k-subset)
        float sv[16];
        float vmax = -1e30f;
#pragma unroll
        for (int mf = 0; mf < 4; mf++)
#pragma unroll
            for (int r = 0; r < 4; r++) {
                int kg = kt * 64 + mf * 16 + lg * 4 + r;
                float v = acc_s[mf][r];
                if (kg > q_glob) v = -1e30f;
                sv[mf * 4 + r] = v;
                vmax = fmaxf(vmax, v);
            }
        vmax = fmaxf(vmax, __shfl_xor(vmax, 16));
        vmax = fmaxf(vmax, __shfl_xor(vmax, 32));
        float m_new = fmaxf(m_i, vmax);
        float corr = __expf(m_i - m_new);
        float rowsum = 0.f;
#pragma unroll
        for (int i = 0; i < 16; i++) {
            float p = __expf(sv[i] - m_new);
            sv[i] = p;
            rowsum += p;
        }
        rowsum += __shfl_xor(rowsum, 16);
        rowsum += __shfl_xor(rowsum, 32);
        l_i = l_i * corr + rowsum;
        m_i = m_new;
        // P -> per-wave LDS, layout [q][k]
#pragma unroll
        for (int mf = 0; mf < 4; mf++) {
            ushort4_t pk;
#pragma unroll
            for (int r = 0; r < 4; r++) pk[r] = f2bf(sv[mf * 4 + r]);
            *(ushort4_t*)&P_lds[wid][l15][mf * 16 + lg * 4] = pk;
        }
        // rescale O accumulator (its rows live at (lg*4+r), fetch corr from lane q')
#pragma unroll
        for (int r = 0; r < 4; r++) {
            float c4 = __shfl(corr, lg * 4 + r);
#pragma unroll
            for (int nf = 0; nf < 4; nf++) acc_o[nf][r] *= c4;
        }
        // PV: O += P . V   (A = P rows, B = Vt rows -> P * V)
#pragma unroll
        for (int s2 = 0; s2 < 2; s2++) {
            short8 pa = *(const short8*)&P_lds[wid][l15][s2 * 32 + lg * 8];
#pragma unroll
            for (int nf = 0; nf < 4; nf++) {
                short8 bv = *(const short8*)&Vt_lds[nf * 16 + l15][s2 * 32 + lg * 8];
                acc_o[nf] = __builtin_amdgcn_mfma_f32_16x16x32_bf16(
                    pa, bv, acc_o[nf], 0, 0, 0);
            }
        }
        __syncthreads();
    }
    // epilogue: O[q][d] / l  ; O rows at (lg*4+r), cols nf*16+l15
    unsigned short* Ob = O + (size_t)(b * S_LEN + qt * 64 + wid * 16) * E_DIM + h * 64;
#pragma unroll
    for (int r = 0; r < 4; r++) {
        float linv = 1.f / __shfl(l_i, lg * 4 + r);
#pragma unroll
        for (int nf = 0; nf < 4; nf++)
            Ob[(size_t)(lg * 4 + r) * E_DIM + nf * 16 + l15] =
                f2bf(acc_o[nf][r] * linv);
    }
}

extern "C" void kernel_launch(void* const* d_in, const int* in_sizes, int n_in,
                              void* d_out, int out_size, void* d_ws, size_t ws_size,
                              hipStream_t stream) {
    (void)in_sizes; (void)n_in; (void)out_size; (void)ws_size;
    const float* x  = (const float*)d_in[0];
    const float* Wq = (const float*)d_in[1];
    const float* Wk = (const float*)d_in[2];
    const float* Wv = (const float*)d_in[3];
    const float* Wo = (const float*)d_in[4];

    unsigned short* us = (unsigned short*)d_ws;
    unsigned short* xb  = us;                    // 4096x1024
    unsigned short* WqT = us + 4194304;          // 1024x1024 each
    unsigned short* WkT = us + 5242880;
    unsigned short* WvT = us + 6291456;
    unsigned short* WoT = us + 7340032;
    unsigned short* Qb  = us + 8388608;          // 4096x1024
    unsigned short* Kb  = us + 12582912;
    unsigned short* Vb  = us + 16777216;
    unsigned short* AO  = us + 20971520;
    float* cosT = (float*)((char*)d_ws + 50331648);
    float* sinT = cosT + 65536;

    k_convert<<<2048, 256, 0, stream>>>(x, xb);
    k_transw<<<dim3(32, 32, 4), dim3(32, 8), 0, stream>>>(Wq, Wk, Wv, Wo,
                                                          WqT, WkT, WvT, WoT);
    k_rope_table<<<256, 256, 0, stream>>>(cosT, sinT);
    k_gemm<false><<<dim3(8, 32, 3), 256, 0, stream>>>(xb, WqT, WkT, WvT,
                                                      Qb, Kb, Vb);
    k_rope<<<dim3(2048, 2), 256, 0, stream>>>(Qb, Kb, cosT, sinT);
    k_attn<<<dim3(32, 32), 256, 0, stream>>>(Qb, Kb, Vb, AO);
    k_gemm<true><<<dim3(8, 32, 1), 256, 0, stream>>>(AO, WoT, WoT, WoT,
                                                     d_out, d_out, d_out);
}

// Round 2
// 154.160 us; speedup vs baseline: 1.4058x; 1.4058x over previous
//
#include <hip/hip_runtime.h>
#include <hip/hip_bf16.h>

#define S_LEN 2048
#define E_DIM 1024
#define NH 16
#define HD 64
#define ATTN_SCALE 0.03125f   // 1/sqrt(1024)
#define KVB 128

typedef __attribute__((ext_vector_type(8))) short short8;
typedef __attribute__((ext_vector_type(8))) unsigned short ushort8;
typedef __attribute__((ext_vector_type(4))) unsigned short ushort4_t;
typedef __attribute__((ext_vector_type(4))) float f32x4;
typedef __attribute__((ext_vector_type(4))) float f4;

__device__ __forceinline__ float bf2f(unsigned short u) {
    unsigned int x = ((unsigned int)u) << 16;
    return __builtin_bit_cast(float, x);
}
__device__ __forceinline__ unsigned short f2bf(float f) {
    unsigned int x = __builtin_bit_cast(unsigned int, f);
    x += 0x7FFFu + ((x >> 16) & 1u);   // RNE
    return (unsigned short)(x >> 16);
}
__device__ __forceinline__ void gload16(const unsigned short* g, unsigned short* l) {
    __builtin_amdgcn_global_load_lds(
        (__attribute__((address_space(1))) void*)g,
        (__attribute__((address_space(3))) void*)l, 16, 0, 0);
}

// ---------------- x f32 -> bf16 ----------------
__global__ __launch_bounds__(256) void k_convert(const float* __restrict__ x,
                                                 unsigned short* __restrict__ xb) {
    size_t i = ((size_t)blockIdx.x * 256 + threadIdx.x) * 8;
    f4 a = *(const f4*)(x + i);
    f4 b = *(const f4*)(x + i + 4);
    ushort8 o;
    o[0] = f2bf(a[0]); o[1] = f2bf(a[1]); o[2] = f2bf(a[2]); o[3] = f2bf(a[3]);
    o[4] = f2bf(b[0]); o[5] = f2bf(b[1]); o[6] = f2bf(b[2]); o[7] = f2bf(b[3]);
    *(ushort8*)(xb + i) = o;
}

// ---------------- W f32 -> bf16 transposed (Wt[n][k] = W[k][n]) ----------------
__global__ __launch_bounds__(256) void k_transw(const float* W0, const float* W1,
                                                const float* W2, const float* W3,
                                                unsigned short* T0, unsigned short* T1,
                                                unsigned short* T2, unsigned short* T3) {
    const float* W; unsigned short* T;
    switch (blockIdx.z) {
        case 0: W = W0; T = T0; break;
        case 1: W = W1; T = T1; break;
        case 2: W = W2; T = T2; break;
        default: W = W3; T = T3; break;
    }
    __shared__ float tile[32][33];
    int tx = threadIdx.x, ty = threadIdx.y;
    int bx = blockIdx.x * 32, by = blockIdx.y * 32;
#pragma unroll
    for (int i = 0; i < 4; i++)
        tile[ty + i * 8][tx] = W[(size_t)(by + ty + i * 8) * E_DIM + bx + tx];
    __syncthreads();
#pragma unroll
    for (int i = 0; i < 4; i++)
        T[(size_t)(bx + ty + i * 8) * E_DIM + by + tx] = f2bf(tile[tx][ty + i * 8]);
}

// ---------------- RoPE cos/sin table: [2048][32] ----------------
__global__ __launch_bounds__(256) void k_rope_table(float* __restrict__ cosT,
                                                    float* __restrict__ sinT) {
    int idx = blockIdx.x * 256 + threadIdx.x;
    int s = idx >> 5, j = idx & 31;
    float inv = expf(-(float)j * (9.210340371976184f / 32.f));
    float ang = (float)s * inv;
    cosT[idx] = cosf(ang);
    sinT[idx] = sinf(ang);
}

// ---------------- in-place interleaved RoPE on bf16 [4096][1024]; Q also scaled ----------------
__global__ __launch_bounds__(256) void k_rope(unsigned short* Qb, unsigned short* Kb,
                                              const float* __restrict__ cosT,
                                              const float* __restrict__ sinT) {
    unsigned short* T = blockIdx.y ? Kb : Qb;
    float sc = blockIdx.y ? 1.f : ATTN_SCALE;
    size_t chunk = (size_t)blockIdx.x * 256 + threadIdx.x;
    int row = (int)(chunk >> 7);
    int colb = (int)(chunk & 127) * 8;
    int s = row & (S_LEN - 1);
    int j0 = (colb & 63) >> 1;
    ushort8 u = *(ushort8*)(T + (size_t)row * E_DIM + colb);
#pragma unroll
    for (int i = 0; i < 4; i++) {
        float c = cosT[s * 32 + j0 + i], sn = sinT[s * 32 + j0 + i];
        float e = bf2f(u[2 * i]), o = bf2f(u[2 * i + 1]);
        float oe = (e * c - o * sn) * sc;
        float oo = (e * sn + o * c) * sc;
        u[2 * i] = f2bf(oe);
        u[2 * i + 1] = f2bf(oo);
    }
    *(ushort8*)(T + (size_t)row * E_DIM + colb) = u;
}

// ---------------- bf16 GEMM (m97 structure): C = A * Bt^T ----------------
// Linear LDS, global_load_lds width-16 staging, 128x128 tile, BK=32.
// QKV: z in {0,1,2}: B={Wq,Wk,Wv}; z<2 -> bf16 C; z==2 -> Vt[b][h][d][s] layout.
template <bool OUT_F32, bool QKV>
__global__ __launch_bounds__(256) void k_gemm(const unsigned short* __restrict__ A,
                                              const unsigned short* __restrict__ B0,
                                              const unsigned short* __restrict__ B1,
                                              const unsigned short* __restrict__ B2,
                                              void* C0, void* C1,
                                              unsigned short* __restrict__ VtOut) {
    int z = QKV ? blockIdx.z : 0;
    const unsigned short* Bp = QKV ? ((z == 0) ? B0 : (z == 1) ? B1 : B2) : B0;
    void* Cp = (z == 0) ? C0 : C1;     // unused for z==2
    __shared__ unsigned short Alds[4096];   // [128][32] linear
    __shared__ unsigned short Blds[4096];
    int tid = threadIdx.x, lane = tid & 63, wid = tid >> 6;
    int l15 = lane & 15, lg = lane >> 4;
    int wr = wid >> 1, wc = wid & 1;
    int bm = blockIdx.y, bn = blockIdx.x;
    // staging: 8 chunks of 1KB each for A and B; wave w owns chunks 2w, 2w+1
    int c0 = wid * 2, c1 = wid * 2 + 1;
    int srow0 = c0 * 16 + (lane >> 2);
    int srow1 = c1 * 16 + (lane >> 2);
    int scol = (lane & 3) * 8;
    const unsigned short* As0 = A + (size_t)(bm * 128 + srow0) * E_DIM + scol;
    const unsigned short* As1 = A + (size_t)(bm * 128 + srow1) * E_DIM + scol;
    const unsigned short* Bs0 = Bp + (size_t)(bn * 128 + srow0) * E_DIM + scol;
    const unsigned short* Bs1 = Bp + (size_t)(bn * 128 + srow1) * E_DIM + scol;
    unsigned short* Ad0 = Alds + c0 * 512;
    unsigned short* Ad1 = Alds + c1 * 512;
    unsigned short* Bd0 = Blds + c0 * 512;
    unsigned short* Bd1 = Blds + c1 * 512;
    f32x4 acc[4][4] = {};
    for (int k0 = 0; k0 < E_DIM; k0 += 32) {
        gload16(As0 + k0, Ad0);
        gload16(As1 + k0, Ad1);
        gload16(Bs0 + k0, Bd0);
        gload16(Bs1 + k0, Bd1);
        __syncthreads();
        short8 af[4], bfr[4];
#pragma unroll
        for (int mf = 0; mf < 4; mf++)
            af[mf] = *(const short8*)(Alds + (wr * 64 + mf * 16 + l15) * 32 + lg * 8);
#pragma unroll
        for (int nf = 0; nf < 4; nf++)
            bfr[nf] = *(const short8*)(Blds + (wc * 64 + nf * 16 + l15) * 32 + lg * 8);
#pragma unroll
        for (int mf = 0; mf < 4; mf++)
#pragma unroll
            for (int nf = 0; nf < 4; nf++)
                acc[mf][nf] = __builtin_amdgcn_mfma_f32_16x16x32_bf16(
                    af[mf], bfr[nf], acc[mf][nf], 0, 0, 0);
        __syncthreads();
    }
    if (QKV && z == 2) {
        // write V transposed: Vt[((b*16+h)*64+d)*2048 + s]
        int b = bm >> 4;
#pragma unroll
        for (int mf = 0; mf < 4; mf++) {
            int sb = (bm & 15) * 128 + wr * 64 + mf * 16 + lg * 4;
#pragma unroll
            for (int nf = 0; nf < 4; nf++) {
                int col = bn * 128 + wc * 64 + nf * 16 + l15;
                int h = col >> 6, d = col & 63;
                ushort4_t p;
#pragma unroll
                for (int r = 0; r < 4; r++) p[r] = f2bf(acc[mf][nf][r]);
                *(ushort4_t*)(VtOut + (((size_t)((b * 16 + h) * 64 + d)) << 11) + sb) = p;
            }
        }
    } else {
#pragma unroll
        for (int mf = 0; mf < 4; mf++)
#pragma unroll
            for (int r = 0; r < 4; r++) {
                size_t row = (size_t)(bm * 128 + wr * 64 + mf * 16 + lg * 4 + r);
#pragma unroll
                for (int nf = 0; nf < 4; nf++) {
                    size_t col = (size_t)(bn * 128 + wc * 64 + nf * 16 + l15);
                    float v = acc[mf][nf][r];
                    if (OUT_F32)
                        ((float*)Cp)[row * E_DIM + col] = v;
                    else
                        ((unsigned short*)Cp)[row * E_DIM + col] = f2bf(v);
                }
            }
    }
}

// ---------------- causal flash attention, bf16 ----------------
// Block: 4 waves x 16 q-rows = 64 q-rows; processes q-tile pair (j, 31-j) -> 17 KV
// tiles of 128 per block, perfectly balanced. V pre-transposed globally (Vt[bh][d][s]).
__global__ __launch_bounds__(256) void k_attn(const unsigned short* __restrict__ Q,
                                              const unsigned short* __restrict__ K,
                                              const unsigned short* __restrict__ Vt,
                                              unsigned short* __restrict__ O) {
    __shared__ unsigned short K_lds[128][72];     // [k][d]
    __shared__ unsigned short Vt_lds[64][136];    // [d][k]
    __shared__ unsigned short P_lds[4][16][136];  // per-wave [q][k]
    int tid = threadIdx.x, lane = tid & 63, wid = tid >> 6;
    int l15 = lane & 15, lg = lane >> 4;
    int jp = blockIdx.x;            // 0..15
    int bh = blockIdx.y;            // 0..31
    int b = bh >> 4, h = bh & 15;
    const size_t base_qk = (size_t)b * S_LEN * E_DIM + (size_t)h * HD;
    const unsigned short* Vbh = Vt + ((size_t)(bh * 64) << 11);

    for (int pass = 0; pass < 2; ++pass) {
        int qt = pass ? (31 - jp) : jp;
        const unsigned short* Qb = Q + base_qk + (size_t)(qt * 64 + wid * 16) * E_DIM;
        short8 bq[2];
#pragma unroll
        for (int s2 = 0; s2 < 2; s2++)
            bq[s2] = *(const short8*)(Qb + (size_t)l15 * E_DIM + s2 * 32 + lg * 8);
        f32x4 acc_o[4] = {};
        float m_i = -1e30f, l_i = 0.f;
        int q_glob = qt * 64 + wid * 16 + l15;
        int nkt = (qt + 2) >> 1;    // KV tiles of 128
        for (int kt = 0; kt < nkt; ++kt) {
            const unsigned short* Kb = K + base_qk + (size_t)(kt * KVB) * E_DIM;
            const unsigned short* Vb = Vbh + kt * KVB;
#pragma unroll
            for (int i = 0; i < 4; i++) {
                int c = tid + i * 256;           // 1024 chunks each
                int r = c >> 3, c8 = c & 7;
                *(short8*)&K_lds[r][c8 * 8] =
                    *(const short8*)(Kb + (size_t)r * E_DIM + c8 * 8);
                int d = c >> 4, k16 = c & 15;
                *(short8*)&Vt_lds[d][k16 * 8] =
                    *(const short8*)(Vb + ((size_t)d << 11) + k16 * 8);
            }
            __syncthreads();
            // S^T = K . Q^T (scale pre-folded into Q)
            f32x4 acc_s[8] = {};
#pragma unroll
            for (int mf = 0; mf < 8; mf++)
#pragma unroll
                for (int s2 = 0; s2 < 2; s2++) {
                    short8 a = *(const short8*)&K_lds[mf * 16 + l15][s2 * 32 + lg * 8];
                    acc_s[mf] = __builtin_amdgcn_mfma_f32_16x16x32_bf16(
                        a, bq[s2], acc_s[mf], 0, 0, 0);
                }
            float sv[32];
            float vmax = -1e30f;
            if (kt == nkt - 1) {   // only the last tile can cross the diagonal
#pragma unroll
                for (int mf = 0; mf < 8; mf++)
#pragma unroll
                    for (int r = 0; r < 4; r++) {
                        int kg = kt * KVB + mf * 16 + lg * 4 + r;
                        float v = acc_s[mf][r];
                        if (kg > q_glob) v = -1e30f;
                        sv[mf * 4 + r] = v;
                        vmax = fmaxf(vmax, v);
                    }
            } else {
#pragma unroll
                for (int mf = 0; mf < 8; mf++)
#pragma unroll
                    for (int r = 0; r < 4; r++) {
                        float v = acc_s[mf][r];
                        sv[mf * 4 + r] = v;
                        vmax = fmaxf(vmax, v);
                    }
            }
            vmax = fmaxf(vmax, __shfl_xor(vmax, 16));
            vmax = fmaxf(vmax, __shfl_xor(vmax, 32));
            float m_new = fmaxf(m_i, vmax);
            float corr = __expf(m_i - m_new);
            float rowsum = 0.f;
#pragma unroll
            for (int i = 0; i < 32; i++) {
                float p = __expf(sv[i] - m_new);
                sv[i] = p;
                rowsum += p;
            }
            rowsum += __shfl_xor(rowsum, 16);
            rowsum += __shfl_xor(rowsum, 32);
            l_i = l_i * corr + rowsum;
            m_i = m_new;
            // P -> per-wave LDS [q][k]
#pragma unroll
            for (int mf = 0; mf < 8; mf++) {
                ushort4_t pk;
#pragma unroll
                for (int r = 0; r < 4; r++) pk[r] = f2bf(sv[mf * 4 + r]);
                *(ushort4_t*)&P_lds[wid][l15][mf * 16 + lg * 4] = pk;
            }
            // rescale O accumulator (rows live at lg*4+r; corr lives at lane q)
#pragma unroll
            for (int r = 0; r < 4; r++) {
                float c4 = __shfl(corr, lg * 4 + r);
#pragma unroll
                for (int nf = 0; nf < 4; nf++) acc_o[nf][r] *= c4;
            }
            // PV: O += P . V
#pragma unroll
            for (int s2 = 0; s2 < 4; s2++) {
                short8 pa = *(const short8*)&P_lds[wid][l15][s2 * 32 + lg * 8];
#pragma unroll
                for (int nf = 0; nf < 4; nf++) {
                    short8 bv = *(const short8*)&Vt_lds[nf * 16 + l15][s2 * 32 + lg * 8];
                    acc_o[nf] = __builtin_amdgcn_mfma_f32_16x16x32_bf16(
                        pa, bv, acc_o[nf], 0, 0, 0);
                }
            }
            __syncthreads();
        }
        unsigned short* Ob = O + base_qk + (size_t)(qt * 64 + wid * 16) * E_DIM;
#pragma unroll
        for (int r = 0; r < 4; r++) {
            float linv = 1.f / __shfl(l_i, lg * 4 + r);
#pragma unroll
            for (int nf = 0; nf < 4; nf++)
                Ob[(size_t)(lg * 4 + r) * E_DIM + nf * 16 + l15] =
                    f2bf(acc_o[nf][r] * linv);
        }
    }
}

extern "C" void kernel_launch(void* const* d_in, const int* in_sizes, int n_in,
                              void* d_out, int out_size, void* d_ws, size_t ws_size,
                              hipStream_t stream) {
    (void)in_sizes; (void)n_in; (void)out_size; (void)ws_size;
    const float* x  = (const float*)d_in[0];
    const float* Wq = (const float*)d_in[1];
    const float* Wk = (const float*)d_in[2];
    const float* Wv = (const float*)d_in[3];
    const float* Wo = (const float*)d_in[4];

    unsigned short* us = (unsigned short*)d_ws;
    unsigned short* xb  = us;                    // 4096x1024
    unsigned short* WqT = us + 4194304;          // 1024x1024 each
    unsigned short* WkT = us + 5242880;
    unsigned short* WvT = us + 6291456;
    unsigned short* WoT = us + 7340032;
    unsigned short* Qb  = us + 8388608;          // 4096x1024
    unsigned short* Kb  = us + 12582912;
    unsigned short* Vt  = us + 16777216;         // [b][h][d][s] = [2][16][64][2048]
    unsigned short* AO  = us + 20971520;
    float* cosT = (float*)((char*)d_ws + 50331648);
    float* sinT = cosT + 65536;

    k_convert<<<2048, 256, 0, stream>>>(x, xb);
    k_transw<<<dim3(32, 32, 4), dim3(32, 8), 0, stream>>>(Wq, Wk, Wv, Wo,
                                                          WqT, WkT, WvT, WoT);
    k_rope_table<<<256, 256, 0, stream>>>(cosT, sinT);
    k_gemm<false, true><<<dim3(8, 32, 3), 256, 0, stream>>>(xb, WqT, WkT, WvT,
                                                            Qb, Kb, Vt);
    k_rope<<<dim3(2048, 2), 256, 0, stream>>>(Qb, Kb, cosT, sinT);
    k_attn<<<dim3(16, 32), 256, 0, stream>>>(Qb, Kb, Vt, AO);
    k_gemm<true, false><<<dim3(8, 32, 1), 256, 0, stream>>>(AO, WoT, WoT, WoT,
                                                            d_out, d_out, Vt);
}

// Round 3
// 131.895 us; speedup vs baseline: 1.6431x; 1.1688x over previous
//
#include <hip/hip_runtime.h>
#include <hip/hip_bf16.h>

#define S_LEN 2048
#define E_DIM 1024
#define NH 16
#define HD 64
#define ATTN_SCALE 0.03125f   // 1/sqrt(1024)
#define KVB 128

typedef __attribute__((ext_vector_type(8))) short short8;
typedef __attribute__((ext_vector_type(8))) unsigned short ushort8;
typedef __attribute__((ext_vector_type(4))) unsigned short ushort4_t;
typedef __attribute__((ext_vector_type(4))) float f32x4;
typedef __attribute__((ext_vector_type(4))) float f4;

__device__ __forceinline__ float bf2f(unsigned short u) {
    unsigned int x = ((unsigned int)u) << 16;
    return __builtin_bit_cast(float, x);
}
__device__ __forceinline__ unsigned short f2bf(float f) {
    unsigned int x = __builtin_bit_cast(unsigned int, f);
    x += 0x7FFFu + ((x >> 16) & 1u);   // RNE
    return (unsigned short)(x >> 16);
}
__device__ __forceinline__ void gload16(const unsigned short* g, unsigned short* l) {
    __builtin_amdgcn_global_load_lds(
        (__attribute__((address_space(1))) void*)g,
        (__attribute__((address_space(3))) void*)l, 16, 0, 0);
}

// ---------------- x f32 -> bf16 ----------------
__global__ __launch_bounds__(256) void k_convert(const float* __restrict__ x,
                                                 unsigned short* __restrict__ xb) {
    size_t i = ((size_t)blockIdx.x * 256 + threadIdx.x) * 8;
    f4 a = *(const f4*)(x + i);
    f4 b = *(const f4*)(x + i + 4);
    ushort8 o;
    o[0] = f2bf(a[0]); o[1] = f2bf(a[1]); o[2] = f2bf(a[2]); o[3] = f2bf(a[3]);
    o[4] = f2bf(b[0]); o[5] = f2bf(b[1]); o[6] = f2bf(b[2]); o[7] = f2bf(b[3]);
    *(ushort8*)(xb + i) = o;
}

// ---------------- W f32 -> bf16 transposed (Wt[n][k] = W[k][n]) ----------------
__global__ __launch_bounds__(256) void k_transw(const float* W0, const float* W1,
                                                const float* W2, const float* W3,
                                                unsigned short* T0, unsigned short* T1,
                                                unsigned short* T2, unsigned short* T3) {
    const float* W; unsigned short* T;
    switch (blockIdx.z) {
        case 0: W = W0; T = T0; break;
        case 1: W = W1; T = T1; break;
        case 2: W = W2; T = T2; break;
        default: W = W3; T = T3; break;
    }
    __shared__ float tile[32][33];
    int tx = threadIdx.x, ty = threadIdx.y;
    int bx = blockIdx.x * 32, by = blockIdx.y * 32;
#pragma unroll
    for (int i = 0; i < 4; i++)
        tile[ty + i * 8][tx] = W[(size_t)(by + ty + i * 8) * E_DIM + bx + tx];
    __syncthreads();
#pragma unroll
    for (int i = 0; i < 4; i++)
        T[(size_t)(bx + ty + i * 8) * E_DIM + by + tx] = f2bf(tile[tx][ty + i * 8]);
}

// ---------------- RoPE cos/sin table: [2048][32] ----------------
__global__ __launch_bounds__(256) void k_rope_table(float* __restrict__ cosT,
                                                    float* __restrict__ sinT) {
    int idx = blockIdx.x * 256 + threadIdx.x;
    int s = idx >> 5, j = idx & 31;
    float inv = expf(-(float)j * (9.210340371976184f / 32.f));
    float ang = (float)s * inv;
    cosT[idx] = cosf(ang);
    sinT[idx] = sinf(ang);
}

// ---------------- in-place interleaved RoPE on bf16 [4096][1024]; Q also scaled ----------------
__global__ __launch_bounds__(256) void k_rope(unsigned short* Qb, unsigned short* Kb,
                                              const float* __restrict__ cosT,
                                              const float* __restrict__ sinT) {
    unsigned short* T = blockIdx.y ? Kb : Qb;
    float sc = blockIdx.y ? 1.f : ATTN_SCALE;
    size_t chunk = (size_t)blockIdx.x * 256 + threadIdx.x;
    int row = (int)(chunk >> 7);
    int colb = (int)(chunk & 127) * 8;
    int s = row & (S_LEN - 1);
    int j0 = (colb & 63) >> 1;
    ushort8 u = *(ushort8*)(T + (size_t)row * E_DIM + colb);
#pragma unroll
    for (int i = 0; i < 4; i++) {
        float c = cosT[s * 32 + j0 + i], sn = sinT[s * 32 + j0 + i];
        float e = bf2f(u[2 * i]), o = bf2f(u[2 * i + 1]);
        float oe = (e * c - o * sn) * sc;
        float oo = (e * sn + o * c) * sc;
        u[2 * i] = f2bf(oe);
        u[2 * i + 1] = f2bf(oo);
    }
    *(ushort8*)(T + (size_t)row * E_DIM + colb) = u;
}

// ---------------- bf16 GEMM, T3 2-phase: dbuf LDS + gload_lds + 1 barrier/K-step ----
// C = A * B^T, A [4096][1024], B [3072 or 1024][1024] (pre-transposed weights).
// LDS linear dest + inverse-swizzled global source + swizzled ds_read (rule 21).
// QKV3: B = [Wq;Wk;Wv], writes Q,K bf16 [4096][1024] and V transposed [bh][d][s].
template <int BM, int BN, int WGM, int WGN, int NBN, bool QKV3>
__global__ __launch_bounds__(WGM * WGN * 64, 2)
void k_gemm2(const unsigned short* __restrict__ A,
             const unsigned short* __restrict__ B,
             unsigned short* __restrict__ Qo,
             unsigned short* __restrict__ Ko,
             unsigned short* __restrict__ Vto,
             float* __restrict__ Fo) {
    constexpr int THREADS = WGM * WGN * 64;
    constexpr int WM = BM / WGM, WN = BN / WGN;
    constexpr int FM = WM / 16, FN = WN / 16;
    constexpr int NT = E_DIM / 64;
    constexpr int AR = BM * 8 / THREADS;     // stage rounds for A
    constexpr int BR = BN * 8 / THREADS;
    constexpr int MB = 4096 / BM;
    constexpr int NWG = MB * NBN;
    __shared__ unsigned short Al[2][BM * 64];
    __shared__ unsigned short Bl[2][BN * 64];
    int tid = threadIdx.x, lane = tid & 63, wid = tid >> 6;
    int l15 = lane & 15, lg = lane >> 4;
    int wr = wid / WGN, wc = wid % WGN;
    int orig = blockIdx.y * NBN + blockIdx.x;
    int wg = (orig & 7) * (NWG / 8) + (orig >> 3);   // bijective XCD swizzle
    int bm = wg / NBN, bn = wg % NBN;

    auto stage = [&](int buf, int k0) {
#pragma unroll
        for (int i = 0; i < AR; i++) {
            int r = i * (THREADS / 8) + wid * 8 + (lane >> 3);
            int cs = (lane & 7) ^ (r & 7);
            gload16(A + (size_t)(bm * BM + r) * E_DIM + k0 + cs * 8,
                    &Al[buf][i * (THREADS * 8) + wid * 512]);
        }
#pragma unroll
        for (int i = 0; i < BR; i++) {
            int r = i * (THREADS / 8) + wid * 8 + (lane >> 3);
            int cs = (lane & 7) ^ (r & 7);
            gload16(B + (size_t)(bn * BN + r) * E_DIM + k0 + cs * 8,
                    &Bl[buf][i * (THREADS * 8) + wid * 512]);
        }
    };

    f32x4 acc[FM][FN] = {};
    int cur = 0;
    stage(0, 0);
    __syncthreads();
    for (int t = 0; t < NT; t++) {
        if (t + 1 < NT) stage(cur ^ 1, (t + 1) * 64);
#pragma unroll
        for (int ks = 0; ks < 2; ks++) {
            short8 af[FM], bfv[FN];
#pragma unroll
            for (int m = 0; m < FM; m++) {
                int r = wr * WM + m * 16 + l15;
                int gc = ks * 4 + lg;
                af[m] = *(const short8*)&Al[cur][r * 64 + ((gc ^ (r & 7)) << 3)];
            }
#pragma unroll
            for (int n = 0; n < FN; n++) {
                int r = wc * WN + n * 16 + l15;
                int gc = ks * 4 + lg;
                bfv[n] = *(const short8*)&Bl[cur][r * 64 + ((gc ^ (r & 7)) << 3)];
            }
#pragma unroll
            for (int m = 0; m < FM; m++)
#pragma unroll
                for (int n = 0; n < FN; n++)
                    acc[m][n] = __builtin_amdgcn_mfma_f32_16x16x32_bf16(
                        af[m], bfv[n], acc[m][n], 0, 0, 0);
        }
        __syncthreads();
        cur ^= 1;
    }
    // epilogue
#pragma unroll
    for (int m = 0; m < FM; m++) {
        int r0 = bm * BM + wr * WM + m * 16 + lg * 4;
#pragma unroll
        for (int n = 0; n < FN; n++) {
            int colg = bn * BN + wc * WN + n * 16 + l15;
            if (QKV3) {
                int z = colg >> 10, c1 = colg & 1023;
                if (z == 2) {
                    int h = c1 >> 6, d = c1 & 63;
                    int bb = r0 >> 11, s = r0 & 2047;
                    ushort4_t p;
#pragma unroll
                    for (int r = 0; r < 4; r++) p[r] = f2bf(acc[m][n][r]);
                    *(ushort4_t*)(Vto + (((size_t)((bb * 16 + h) * 64 + d)) << 11) + s) = p;
                } else {
                    unsigned short* T = z ? Ko : Qo;
#pragma unroll
                    for (int r = 0; r < 4; r++)
                        T[(size_t)(r0 + r) * E_DIM + c1] = f2bf(acc[m][n][r]);
                }
            } else {
#pragma unroll
                for (int r = 0; r < 4; r++)
                    Fo[(size_t)(r0 + r) * E_DIM + colg] = acc[m][n][r];
            }
        }
    }
}

// ---------------- causal flash attention, bf16, pipelined single-buffer ----------
// 4 waves x 16 q-rows; q-tile pair (j, 31-j) -> 17 KV tiles of 128 per block.
// K/Vt staged via gload_lds (linear dest, swizzled source), swizzled ds_read.
// stage K(t+1) hides under softmax+PV; stage V(t+1) hides under next QK.
__global__ __launch_bounds__(256, 2) void k_attn(const unsigned short* __restrict__ Q,
                                                 const unsigned short* __restrict__ K,
                                                 const unsigned short* __restrict__ Vt,
                                                 unsigned short* __restrict__ O) {
    __shared__ unsigned short K_lds[128 * 64];
    __shared__ unsigned short V_lds[64 * 128];
    __shared__ unsigned short P_lds[4][16][136];
    int tid = threadIdx.x, lane = tid & 63, wid = tid >> 6;
    int l15 = lane & 15, lg = lane >> 4;
    int orig = blockIdx.y * 16 + blockIdx.x;         // 512 wgs
    int wg = (orig & 7) * 64 + (orig >> 3);          // XCD swizzle
    int jp = wg & 15, bh = wg >> 4;
    int b = bh >> 4, h = bh & 15;
    const size_t base_qk = (size_t)b * S_LEN * E_DIM + (size_t)h * HD;
    const unsigned short* Vbh = Vt + ((size_t)(bh * 64) << 11);

    auto stageK = [&](int kt) {
        const unsigned short* Kb = K + base_qk + (size_t)(kt * KVB) * E_DIM;
#pragma unroll
        for (int i = 0; i < 4; i++) {
            int r = i * 32 + wid * 8 + (lane >> 3);
            int cs = (lane & 7) ^ (r & 7);
            gload16(Kb + (size_t)r * E_DIM + cs * 8, K_lds + i * 2048 + wid * 512);
        }
    };
    auto stageV = [&](int kt) {
#pragma unroll
        for (int i = 0; i < 4; i++) {
            int r = i * 16 + wid * 4 + (lane >> 4);
            int cs = (lane & 15) ^ (r & 7);
            gload16(Vbh + (size_t)r * 2048 + kt * KVB + cs * 8,
                    V_lds + i * 2048 + wid * 512);
        }
    };

    for (int pass = 0; pass < 2; ++pass) {
        int qt = pass ? (31 - jp) : jp;
        const unsigned short* Qb = Q + base_qk + (size_t)(qt * 64 + wid * 16) * E_DIM;
        short8 bq[2];
#pragma unroll
        for (int s2 = 0; s2 < 2; s2++)
            bq[s2] = *(const short8*)(Qb + (size_t)l15 * E_DIM + s2 * 32 + lg * 8);
        f32x4 acc_o[4] = {};
        float m_i = -1e30f, l_i = 0.f;
        int q_glob = qt * 64 + wid * 16 + l15;
        int nkt = (qt + 2) >> 1;
        stageK(0);
        stageV(0);
        __syncthreads();
        for (int kt = 0; kt < nkt; ++kt) {
            // S^T = K . Q^T (scale pre-folded into Q)
            f32x4 acc_s[8] = {};
            __builtin_amdgcn_s_setprio(1);
#pragma unroll
            for (int mf = 0; mf < 8; mf++) {
                int rK = mf * 16 + l15;
#pragma unroll
                for (int s2 = 0; s2 < 2; s2++) {
                    int gc = s2 * 4 + lg;
                    short8 a = *(const short8*)&K_lds[rK * 64 + ((gc ^ (rK & 7)) << 3)];
                    acc_s[mf] = __builtin_amdgcn_mfma_f32_16x16x32_bf16(
                        a, bq[s2], acc_s[mf], 0, 0, 0);
                }
            }
            __builtin_amdgcn_s_setprio(0);
            __syncthreads();                    // [A] K reads done; V(kt) writes drained
            if (kt + 1 < nkt) stageK(kt + 1);   // hides under softmax+PV
            float sv[32];
            float vmax = -1e30f;
            if (kt == nkt - 1) {
#pragma unroll
                for (int mf = 0; mf < 8; mf++)
#pragma unroll
                    for (int r = 0; r < 4; r++) {
                        int kg = kt * KVB + mf * 16 + lg * 4 + r;
                        float v = acc_s[mf][r];
                        if (kg > q_glob) v = -1e30f;
                        sv[mf * 4 + r] = v;
                        vmax = fmaxf(vmax, v);
                    }
            } else {
#pragma unroll
                for (int mf = 0; mf < 8; mf++)
#pragma unroll
                    for (int r = 0; r < 4; r++) {
                        float v = acc_s[mf][r];
                        sv[mf * 4 + r] = v;
                        vmax = fmaxf(vmax, v);
                    }
            }
            vmax = fmaxf(vmax, __shfl_xor(vmax, 16));
            vmax = fmaxf(vmax, __shfl_xor(vmax, 32));
            float m_new = fmaxf(m_i, vmax);
            float corr = __expf(m_i - m_new);
            float rowsum = 0.f;
#pragma unroll
            for (int i = 0; i < 32; i++) {
                float p = __expf(sv[i] - m_new);
                sv[i] = p;
                rowsum += p;
            }
            rowsum += __shfl_xor(rowsum, 16);
            rowsum += __shfl_xor(rowsum, 32);
            l_i = l_i * corr + rowsum;
            m_i = m_new;
            // P -> per-wave LDS [q][k] (no barrier: wave-private)
#pragma unroll
            for (int mf = 0; mf < 8; mf++) {
                ushort4_t pk;
#pragma unroll
                for (int r = 0; r < 4; r++) pk[r] = f2bf(sv[mf * 4 + r]);
                *(ushort4_t*)&P_lds[wid][l15][mf * 16 + lg * 4] = pk;
            }
            // rescale O accumulator (rows at lg*4+r; corr lives at lane q)
#pragma unroll
            for (int r = 0; r < 4; r++) {
                float c4 = __shfl(corr, lg * 4 + r);
#pragma unroll
                for (int nf = 0; nf < 4; nf++) acc_o[nf][r] *= c4;
            }
            // PV: O += P . V
            __builtin_amdgcn_s_setprio(1);
#pragma unroll
            for (int s2 = 0; s2 < 4; s2++) {
                short8 pa = *(const short8*)&P_lds[wid][l15][s2 * 32 + lg * 8];
#pragma unroll
                for (int nf = 0; nf < 4; nf++) {
                    int rV = nf * 16 + l15;
                    int gc = s2 * 4 + lg;
                    short8 bv = *(const short8*)&V_lds[rV * 128 + ((gc ^ (rV & 7)) << 3)];
                    acc_o[nf] = __builtin_amdgcn_mfma_f32_16x16x32_bf16(
                        pa, bv, acc_o[nf], 0, 0, 0);
                }
            }
            __builtin_amdgcn_s_setprio(0);
            __syncthreads();                    // [B] V reads done; K(kt+1) drained
            if (kt + 1 < nkt) stageV(kt + 1);   // hides under next QK
        }
        unsigned short* Ob = O + base_qk + (size_t)(qt * 64 + wid * 16) * E_DIM;
#pragma unroll
        for (int r = 0; r < 4; r++) {
            float linv = 1.f / __shfl(l_i, lg * 4 + r);
#pragma unroll
            for (int nf = 0; nf < 4; nf++)
                Ob[(size_t)(lg * 4 + r) * E_DIM + nf * 16 + l15] =
                    f2bf(acc_o[nf][r] * linv);
        }
    }
}

extern "C" void kernel_launch(void* const* d_in, const int* in_sizes, int n_in,
                              void* d_out, int out_size, void* d_ws, size_t ws_size,
                              hipStream_t stream) {
    (void)in_sizes; (void)n_in; (void)out_size; (void)ws_size;
    const float* x  = (const float*)d_in[0];
    const float* Wq = (const float*)d_in[1];
    const float* Wk = (const float*)d_in[2];
    const float* Wv = (const float*)d_in[3];
    const float* Wo = (const float*)d_in[4];

    unsigned short* us = (unsigned short*)d_ws;
    unsigned short* xb    = us;                  // 4096x1024
    unsigned short* WqkvT = us + 4194304;        // 3072x1024 (Wq;Wk;Wv rows)
    unsigned short* WoT   = us + 7340032;        // 1024x1024
    unsigned short* Qb    = us + 8388608;        // 4096x1024
    unsigned short* Kb    = us + 12582912;
    unsigned short* Vt    = us + 16777216;       // [b][h][d][s] = [2][16][64][2048]
    unsigned short* AO    = us + 20971520;
    float* cosT = (float*)((char*)d_ws + 50331648);
    float* sinT = cosT + 65536;

    k_convert<<<2048, 256, 0, stream>>>(x, xb);
    k_transw<<<dim3(32, 32, 4), dim3(32, 8), 0, stream>>>(
        Wq, Wk, Wv, Wo, WqkvT, WqkvT + 1048576, WqkvT + 2097152, WoT);
    k_rope_table<<<256, 256, 0, stream>>>(cosT, sinT);
    k_gemm2<256, 256, 2, 4, 12, true><<<dim3(12, 16), 512, 0, stream>>>(
        xb, WqkvT, Qb, Kb, Vt, nullptr);
    k_rope<<<dim3(2048, 2), 256, 0, stream>>>(Qb, Kb, cosT, sinT);
    k_attn<<<dim3(16, 32), 256, 0, stream>>>(Qb, Kb, Vt, AO);
    k_gemm2<128, 128, 2, 2, 8, false><<<dim3(8, 32), 256, 0, stream>>>(
        AO, WoT, nullptr, nullptr, nullptr, (float*)d_out);
}

// Round 4
// 114.979 us; speedup vs baseline: 1.8849x; 1.1471x over previous
//
#include <hip/hip_runtime.h>
#include <hip/hip_bf16.h>

#define S_LEN 2048
#define E_DIM 1024
#define NH 16
#define HD 64
#define ATTN_SCALE 0.03125f   // 1/sqrt(1024)
#define KVB 128

typedef __attribute__((ext_vector_type(8))) short short8;
typedef __attribute__((ext_vector_type(8))) unsigned short ushort8;
typedef __attribute__((ext_vector_type(4))) unsigned short ushort4_t;
typedef __attribute__((ext_vector_type(4))) float f32x4;
typedef __attribute__((ext_vector_type(4))) float f4;

__device__ __forceinline__ float bf2f(unsigned short u) {
    unsigned int x = ((unsigned int)u) << 16;
    return __builtin_bit_cast(float, x);
}
__device__ __forceinline__ unsigned short f2bf(float f) {
    unsigned int x = __builtin_bit_cast(unsigned int, f);
    x += 0x7FFFu + ((x >> 16) & 1u);   // RNE
    return (unsigned short)(x >> 16);
}
__device__ __forceinline__ void gload16(const unsigned short* g, unsigned short* l) {
    __builtin_amdgcn_global_load_lds(
        (__attribute__((address_space(1))) void*)g,
        (__attribute__((address_space(3))) void*)l, 16, 0, 0);
}

// ---------------- x f32 -> bf16 ----------------
__global__ __launch_bounds__(256) void k_convert(const float* __restrict__ x,
                                                 unsigned short* __restrict__ xb) {
    size_t i = ((size_t)blockIdx.x * 256 + threadIdx.x) * 8;
    f4 a = *(const f4*)(x + i);
    f4 b = *(const f4*)(x + i + 4);
    ushort8 o;
    o[0] = f2bf(a[0]); o[1] = f2bf(a[1]); o[2] = f2bf(a[2]); o[3] = f2bf(a[3]);
    o[4] = f2bf(b[0]); o[5] = f2bf(b[1]); o[6] = f2bf(b[2]); o[7] = f2bf(b[3]);
    *(ushort8*)(xb + i) = o;
}

// ---------------- W f32 -> bf16 transposed (Wt[n][k] = W[k][n]) ----------------
__global__ __launch_bounds__(256) void k_transw(const float* W0, const float* W1,
                                                const float* W2, const float* W3,
                                                unsigned short* T0, unsigned short* T1,
                                                unsigned short* T2, unsigned short* T3) {
    const float* W; unsigned short* T;
    switch (blockIdx.z) {
        case 0: W = W0; T = T0; break;
        case 1: W = W1; T = T1; break;
        case 2: W = W2; T = T2; break;
        default: W = W3; T = T3; break;
    }
    __shared__ float tile[32][33];
    int tx = threadIdx.x, ty = threadIdx.y;
    int bx = blockIdx.x * 32, by = blockIdx.y * 32;
#pragma unroll
    for (int i = 0; i < 4; i++)
        tile[ty + i * 8][tx] = W[(size_t)(by + ty + i * 8) * E_DIM + bx + tx];
    __syncthreads();
#pragma unroll
    for (int i = 0; i < 4; i++)
        T[(size_t)(bx + ty + i * 8) * E_DIM + by + tx] = f2bf(tile[tx][ty + i * 8]);
}

// ---------------- RoPE cos/sin table: [2048][32] ----------------
__global__ __launch_bounds__(256) void k_rope_table(float* __restrict__ cosT,
                                                    float* __restrict__ sinT) {
    int idx = blockIdx.x * 256 + threadIdx.x;
    int s = idx >> 5, j = idx & 31;
    float inv = expf(-(float)j * (9.210340371976184f / 32.f));
    float ang = (float)s * inv;
    cosT[idx] = cosf(ang);
    sinT[idx] = sinf(ang);
}

// ---------------- bf16 GEMM, counted-vmcnt 2-phase (T3/T4) ----------------
// C = A * B^T. Raw s_barrier, prefetch stays in flight (vmcnt(STG)), dbuf LDS.
// QKV3: B = [Wq;Wk;Wv] -> writes RoPE'd Q (scaled), RoPE'd K, V transposed.
template <int BM, int BN, int WGM, int WGN, int NBN, bool QKV3>
__global__ __launch_bounds__(WGM * WGN * 64, 2)
void k_gemm2(const unsigned short* __restrict__ A,
             const unsigned short* __restrict__ B,
             unsigned short* __restrict__ Qo,
             unsigned short* __restrict__ Ko,
             unsigned short* __restrict__ Vto,
             float* __restrict__ Fo,
             const float* __restrict__ cosT,
             const float* __restrict__ sinT) {
    constexpr int THREADS = WGM * WGN * 64;
    constexpr int WM = BM / WGM, WN = BN / WGN;
    constexpr int FM = WM / 16, FN = WN / 16;
    constexpr int NT = E_DIM / 64;
    constexpr int AR = BM * 8 / THREADS;
    constexpr int BR = BN * 8 / THREADS;
    constexpr int STG = AR + BR;
    constexpr int MB = 4096 / BM;
    constexpr int NWG = MB * NBN;
    __shared__ unsigned short Al[2][BM * 64];
    __shared__ unsigned short Bl[2][BN * 64];
    int tid = threadIdx.x, lane = tid & 63, wid = tid >> 6;
    int l15 = lane & 15, lg = lane >> 4;
    int wr = wid / WGN, wc = wid % WGN;
    int orig = blockIdx.y * NBN + blockIdx.x;
    int wg = (orig & 7) * (NWG / 8) + (orig >> 3);   // bijective XCD swizzle
    int bm = wg / NBN, bn = wg % NBN;

    auto stage = [&](int buf, int k0) {
#pragma unroll
        for (int i = 0; i < AR; i++) {
            int r = i * (THREADS / 8) + wid * 8 + (lane >> 3);
            int cs = (lane & 7) ^ (r & 7);
            gload16(A + (size_t)(bm * BM + r) * E_DIM + k0 + cs * 8,
                    &Al[buf][i * (THREADS * 8) + wid * 512]);
        }
#pragma unroll
        for (int i = 0; i < BR; i++) {
            int r = i * (THREADS / 8) + wid * 8 + (lane >> 3);
            int cs = (lane & 7) ^ (r & 7);
            gload16(B + (size_t)(bn * BN + r) * E_DIM + k0 + cs * 8,
                    &Bl[buf][i * (THREADS * 8) + wid * 512]);
        }
    };

    f32x4 acc[FM][FN] = {};
    stage(0, 0);
    for (int t = 0; t < NT; t++) {
        int cur = t & 1;
        if (t + 1 < NT) {
            stage(cur ^ 1, (t + 1) * 64);
            asm volatile("s_waitcnt vmcnt(%0)" :: "n"(STG) : "memory");
        } else {
            asm volatile("s_waitcnt vmcnt(0)" ::: "memory");
        }
        __builtin_amdgcn_s_barrier();          // tile t fully in LDS (all waves)
        __builtin_amdgcn_sched_barrier(0);
#pragma unroll
        for (int ks = 0; ks < 2; ks++) {
            short8 af[FM], bfv[FN];
#pragma unroll
            for (int m = 0; m < FM; m++) {
                int r = wr * WM + m * 16 + l15;
                int gc = ks * 4 + lg;
                af[m] = *(const short8*)&Al[cur][r * 64 + ((gc ^ (r & 7)) << 3)];
            }
#pragma unroll
            for (int n = 0; n < FN; n++) {
                int r = wc * WN + n * 16 + l15;
                int gc = ks * 4 + lg;
                bfv[n] = *(const short8*)&Bl[cur][r * 64 + ((gc ^ (r & 7)) << 3)];
            }
#pragma unroll
            for (int m = 0; m < FM; m++)
#pragma unroll
                for (int n = 0; n < FN; n++)
                    acc[m][n] = __builtin_amdgcn_mfma_f32_16x16x32_bf16(
                        af[m], bfv[n], acc[m][n], 0, 0, 0);
        }
        __builtin_amdgcn_s_barrier();          // all waves done reading tile t
    }
    // epilogue
#pragma unroll
    for (int m = 0; m < FM; m++) {
        int r0 = bm * BM + wr * WM + m * 16 + lg * 4;
#pragma unroll
        for (int n = 0; n < FN; n++) {
            int colg = bn * BN + wc * WN + n * 16 + l15;
            if (QKV3) {
                int z = colg >> 10, c1 = colg & 1023;
                if (z == 2) {
                    int h = c1 >> 6, d = c1 & 63;
                    int bb = r0 >> 11, s = r0 & 2047;
                    ushort4_t p;
#pragma unroll
                    for (int r = 0; r < 4; r++) p[r] = f2bf(acc[m][n][r]);
                    *(ushort4_t*)(Vto + (((size_t)((bb * 16 + h) * 64 + d)) << 11) + s) = p;
                } else {
                    // fused interleaved RoPE (+ Q scale)
                    unsigned short* T = z ? Ko : Qo;
                    int dl = c1 & 63, j = dl >> 1;
                    float sgn = (dl & 1) ? 1.f : -1.f;
                    float sc = z ? 1.f : ATTN_SCALE;
#pragma unroll
                    for (int r = 0; r < 4; r++) {
                        int row = r0 + r, s = row & 2047;
                        float c = cosT[s * 32 + j], sn = sinT[s * 32 + j];
                        float v = acc[m][n][r];
                        float p = __shfl_xor(v, 1);
                        T[(size_t)row * E_DIM + c1] = f2bf((v * c + sgn * p * sn) * sc);
                    }
                }
            } else {
#pragma unroll
                for (int r = 0; r < 4; r++)
                    Fo[(size_t)(r0 + r) * E_DIM + colg] = acc[m][n][r];
            }
        }
    }
}

// ---------------- causal flash attention, bf16, counted-vmcnt pipeline ----------
// 4 waves x 16 q-rows; q-tile pair (j, 31-j) -> 17 KV tiles of 128 per block.
// 4 light raw barriers per tile, prefetch never drained:
//   QK -> B1 -> stageK(t+1) -> softmax -> vmcnt(4)[V t] -> B2 -> PV -> B3
//   -> stageV(t+1) -> vmcnt(4)[K t+1] -> B4
__global__ __launch_bounds__(256, 2) void k_attn(const unsigned short* __restrict__ Q,
                                                 const unsigned short* __restrict__ K,
                                                 const unsigned short* __restrict__ Vt,
                                                 unsigned short* __restrict__ O) {
    __shared__ unsigned short K_lds[128 * 64];
    __shared__ unsigned short V_lds[64 * 128];
    __shared__ unsigned short P_lds[4][16][136];
    int tid = threadIdx.x, lane = tid & 63, wid = tid >> 6;
    int l15 = lane & 15, lg = lane >> 4;
    int orig = blockIdx.y * 16 + blockIdx.x;         // 512 wgs
    int wg = (orig & 7) * 64 + (orig >> 3);          // XCD swizzle
    int jp = wg & 15, bh = wg >> 4;
    int b = bh >> 4, h = bh & 15;
    const size_t base_qk = (size_t)b * S_LEN * E_DIM + (size_t)h * HD;
    const unsigned short* Vbh = Vt + ((size_t)(bh * 64) << 11);

    auto stageK = [&](int kt) {
        const unsigned short* Kb = K + base_qk + (size_t)(kt * KVB) * E_DIM;
#pragma unroll
        for (int i = 0; i < 4; i++) {
            int r = i * 32 + wid * 8 + (lane >> 3);
            int cs = (lane & 7) ^ (r & 7);
            gload16(Kb + (size_t)r * E_DIM + cs * 8, K_lds + i * 2048 + wid * 512);
        }
    };
    auto stageV = [&](int kt) {
#pragma unroll
        for (int i = 0; i < 4; i++) {
            int r = i * 16 + wid * 4 + (lane >> 4);
            int cs = (lane & 15) ^ (r & 7);
            gload16(Vbh + (size_t)r * 2048 + kt * KVB + cs * 8,
                    V_lds + i * 2048 + wid * 512);
        }
    };

    for (int pass = 0; pass < 2; ++pass) {
        int qt = pass ? (31 - jp) : jp;
        const unsigned short* Qb = Q + base_qk + (size_t)(qt * 64 + wid * 16) * E_DIM;
        short8 bq[2];
#pragma unroll
        for (int s2 = 0; s2 < 2; s2++)
            bq[s2] = *(const short8*)(Qb + (size_t)l15 * E_DIM + s2 * 32 + lg * 8);
        f32x4 acc_o[4] = {};
        float m_i = -1e30f, l_i = 0.f;
        int q_glob = qt * 64 + wid * 16 + l15;
        int nkt = (qt + 2) >> 1;
        stageK(0);
        stageV(0);
        asm volatile("s_waitcnt vmcnt(4)" ::: "memory");   // own K0 (and bq) done
        __builtin_amdgcn_s_barrier();                      // all waves' K0 landed
        __builtin_amdgcn_sched_barrier(0);
        for (int kt = 0; kt < nkt; ++kt) {
            // S^T = K . Q^T (scale pre-folded into Q)
            f32x4 acc_s[8] = {};
            __builtin_amdgcn_s_setprio(1);
#pragma unroll
            for (int mf = 0; mf < 8; mf++) {
                int rK = mf * 16 + l15;
#pragma unroll
                for (int s2 = 0; s2 < 2; s2++) {
                    int gc = s2 * 4 + lg;
                    short8 a = *(const short8*)&K_lds[rK * 64 + ((gc ^ (rK & 7)) << 3)];
                    acc_s[mf] = __builtin_amdgcn_mfma_f32_16x16x32_bf16(
                        a, bq[s2], acc_s[mf], 0, 0, 0);
                }
            }
            __builtin_amdgcn_s_setprio(0);
            __builtin_amdgcn_s_barrier();       // B1: K_lds free
            if (kt + 1 < nkt) stageK(kt + 1);
            float sv[32];
            float vmax = -1e30f;
            if (kt == nkt - 1) {
#pragma unroll
                for (int mf = 0; mf < 8; mf++)
#pragma unroll
                    for (int r = 0; r < 4; r++) {
                        int kg = kt * KVB + mf * 16 + lg * 4 + r;
                        float v = acc_s[mf][r];
                        if (kg > q_glob) v = -1e30f;
                        sv[mf * 4 + r] = v;
                        vmax = fmaxf(vmax, v);
                    }
            } else {
#pragma unroll
                for (int mf = 0; mf < 8; mf++)
#pragma unroll
                    for (int r = 0; r < 4; r++) {
                        float v = acc_s[mf][r];
                        sv[mf * 4 + r] = v;
                        vmax = fmaxf(vmax, v);
                    }
            }
            vmax = fmaxf(vmax, __shfl_xor(vmax, 16));
            vmax = fmaxf(vmax, __shfl_xor(vmax, 32));
            float m_new = fmaxf(m_i, vmax);
            float corr = __expf(m_i - m_new);
            float rowsum = 0.f;
#pragma unroll
            for (int i = 0; i < 32; i++) {
                float p = __expf(sv[i] - m_new);
                sv[i] = p;
                rowsum += p;
            }
            rowsum += __shfl_xor(rowsum, 16);
            rowsum += __shfl_xor(rowsum, 32);
            l_i = l_i * corr + rowsum;
            m_i = m_new;
            // P -> per-wave LDS [q][k] (wave-private)
#pragma unroll
            for (int mf = 0; mf < 8; mf++) {
                ushort4_t pk;
#pragma unroll
                for (int r = 0; r < 4; r++) pk[r] = f2bf(sv[mf * 4 + r]);
                *(ushort4_t*)&P_lds[wid][l15][mf * 16 + lg * 4] = pk;
            }
            // rescale O accumulator (rows at lg*4+r; corr lives at lane q)
#pragma unroll
            for (int r = 0; r < 4; r++) {
                float c4 = __shfl(corr, lg * 4 + r);
#pragma unroll
                for (int nf = 0; nf < 4; nf++) acc_o[nf][r] *= c4;
            }
            if (kt + 1 < nkt)
                asm volatile("s_waitcnt vmcnt(4)" ::: "memory");  // own V(kt) done
            else
                asm volatile("s_waitcnt vmcnt(0)" ::: "memory");
            __builtin_amdgcn_s_barrier();       // B2: all V(kt) landed
            __builtin_amdgcn_sched_barrier(0);
            // PV: O += P . V
            __builtin_amdgcn_s_setprio(1);
#pragma unroll
            for (int s2 = 0; s2 < 4; s2++) {
                short8 pa = *(const short8*)&P_lds[wid][l15][s2 * 32 + lg * 8];
#pragma unroll
                for (int nf = 0; nf < 4; nf++) {
                    int rV = nf * 16 + l15;
                    int gc = s2 * 4 + lg;
                    short8 bv = *(const short8*)&V_lds[rV * 128 + ((gc ^ (rV & 7)) << 3)];
                    acc_o[nf] = __builtin_amdgcn_mfma_f32_16x16x32_bf16(
                        pa, bv, acc_o[nf], 0, 0, 0);
                }
            }
            __builtin_amdgcn_s_setprio(0);
            __builtin_amdgcn_s_barrier();       // B3: V_lds free
            if (kt + 1 < nkt) {
                stageV(kt + 1);
                asm volatile("s_waitcnt vmcnt(4)" ::: "memory");  // own K(kt+1) done
            }
            __builtin_amdgcn_s_barrier();       // B4: all K(kt+1) landed
            __builtin_amdgcn_sched_barrier(0);
        }
        unsigned short* Ob = O + base_qk + (size_t)(qt * 64 + wid * 16) * E_DIM;
#pragma unroll
        for (int r = 0; r < 4; r++) {
            float linv = 1.f / __shfl(l_i, lg * 4 + r);
#pragma unroll
            for (int nf = 0; nf < 4; nf++)
                Ob[(size_t)(lg * 4 + r) * E_DIM + nf * 16 + l15] =
                    f2bf(acc_o[nf][r] * linv);
        }
    }
}

extern "C" void kernel_launch(void* const* d_in, const int* in_sizes, int n_in,
                              void* d_out, int out_size, void* d_ws, size_t ws_size,
                              hipStream_t stream) {
    (void)in_sizes; (void)n_in; (void)out_size; (void)ws_size;
    const float* x  = (const float*)d_in[0];
    const float* Wq = (const float*)d_in[1];
    const float* Wk = (const float*)d_in[2];
    const float* Wv = (const float*)d_in[3];
    const float* Wo = (const float*)d_in[4];

    unsigned short* us = (unsigned short*)d_ws;
    unsigned short* xb    = us;                  // 4096x1024
    unsigned short* WqkvT = us + 4194304;        // 3072x1024 (Wq;Wk;Wv rows)
    unsigned short* WoT   = us + 7340032;        // 1024x1024
    unsigned short* Qb    = us + 8388608;        // 4096x1024 (roped+scaled)
    unsigned short* Kb    = us + 12582912;       // 4096x1024 (roped)
    unsigned short* Vt    = us + 16777216;       // [b][h][d][s] = [2][16][64][2048]
    unsigned short* AO    = us + 20971520;
    float* cosT = (float*)((char*)d_ws + 50331648);
    float* sinT = cosT + 65536;

    k_convert<<<2048, 256, 0, stream>>>(x, xb);
    k_transw<<<dim3(32, 32, 4), dim3(32, 8), 0, stream>>>(
        Wq, Wk, Wv, Wo, WqkvT, WqkvT + 1048576, WqkvT + 2097152, WoT);
    k_rope_table<<<256, 256, 0, stream>>>(cosT, sinT);
    k_gemm2<128, 128, 2, 2, 24, true><<<dim3(24, 32), 256, 0, stream>>>(
        xb, WqkvT, Qb, Kb, Vt, nullptr, cosT, sinT);
    k_attn<<<dim3(16, 32), 256, 0, stream>>>(Qb, Kb, Vt, AO);
    k_gemm2<128, 64, 2, 2, 16, false><<<dim3(16, 32), 256, 0, stream>>>(
        AO, WoT, nullptr, nullptr, nullptr, (float*)d_out, cosT, sinT);
}